// Round 6
// baseline (627.242 us; speedup 1.0000x reference)
//
#include <hip/hip_runtime.h>
#include <cstdint>

#define D 128
#define H 4
#define N_ENT 100000
#define N_EDGE 400000
#define R 32

#define SCAN_NB ((N_ENT + 511) / 512)  // 196 blocks of 512 elements

// ---------------------------------------------------------------------------
// CSR build: histogram -> hierarchical scan -> scatter (permuted packed
// (tail,etype) int2).
// ---------------------------------------------------------------------------
__global__ void k_hist(const int* __restrict__ head, int* __restrict__ deg) {
  const int e = blockIdx.x * 256 + threadIdx.x;
  if (e < N_EDGE) atomicAdd(&deg[head[e]], 1);
}

__global__ __launch_bounds__(256) void k_scan1(const int* __restrict__ deg,
                                               int* __restrict__ bsum) {
  const int t = threadIdx.x;
  const int i = blockIdx.x * 512 + t * 2;
  int v0 = (i < N_ENT) ? deg[i] : 0;
  int v1 = (i + 1 < N_ENT) ? deg[i + 1] : 0;
  int s = v0 + v1;
#pragma unroll
  for (int k = 1; k < 64; k <<= 1) s += __shfl_xor(s, k);
  __shared__ int ws[4];
  if ((t & 63) == 0) ws[t >> 6] = s;
  __syncthreads();
  if (t == 0) bsum[blockIdx.x] = ws[0] + ws[1] + ws[2] + ws[3];
}

__global__ __launch_bounds__(256) void k_scan2(const int* __restrict__ bsum,
                                               int* __restrict__ bbase,
                                               int* __restrict__ off) {
  __shared__ int sh[256];
  const int t = threadIdx.x;
  const int v = (t < SCAN_NB) ? bsum[t] : 0;
  sh[t] = v;
  __syncthreads();
  for (int d = 1; d < 256; d <<= 1) {
    const int u = (t >= d) ? sh[t - d] : 0;
    __syncthreads();
    sh[t] += u;
    __syncthreads();
  }
  if (t < SCAN_NB) bbase[t] = sh[t] - v;
  if (t == SCAN_NB - 1) off[N_ENT] = sh[t];
}

__global__ __launch_bounds__(256) void k_scan3(const int* __restrict__ deg,
                                               const int* __restrict__ bbase,
                                               int* __restrict__ off,
                                               int* __restrict__ cur) {
  __shared__ int sh[256];
  const int t = threadIdx.x;
  const int i = blockIdx.x * 512 + t * 2;
  const int v0 = (i < N_ENT) ? deg[i] : 0;
  const int v1 = (i + 1 < N_ENT) ? deg[i + 1] : 0;
  const int s = v0 + v1;
  sh[t] = s;
  __syncthreads();
  for (int d = 1; d < 256; d <<= 1) {
    const int u = (t >= d) ? sh[t - d] : 0;
    __syncthreads();
    sh[t] += u;
    __syncthreads();
  }
  const int ex = sh[t] - s + bbase[blockIdx.x];
  if (i < N_ENT) {
    off[i] = ex;
    cur[i] = ex;
  }
  if (i + 1 < N_ENT) {
    off[i + 1] = ex + v0;
    cur[i + 1] = ex + v0;
  }
}

__global__ void k_scatter(const int* __restrict__ head,
                          const int* __restrict__ tail,
                          const int* __restrict__ etype, int* __restrict__ cur,
                          int2* __restrict__ teP) {
  const int e = blockIdx.x * 256 + threadIdx.x;
  if (e >= N_EDGE) return;
  const int hd = head[e];
  const int pos = atomicAdd(&cur[hd], 1);
  teP[pos] = make_int2(tail[e], etype[e] - 1);
}

// ---------------------------------------------------------------------------
// k_prep: blocks 0-15: kTt[j*128+i] = kT[i*128+j]; block 16: wrel2 = wrel^2.
// Runs AFTER k_scatter: wrel2 aliases the dead `cur` array.
// ---------------------------------------------------------------------------
__global__ __launch_bounds__(256) void k_prep(const float* __restrict__ kT,
                                              float* __restrict__ kTt,
                                              const float* __restrict__ wrel,
                                              float* __restrict__ wrel2) {
  if (blockIdx.x < 16) {
    __shared__ float tile[32][33];
    const int bx = blockIdx.x & 3, by = blockIdx.x >> 2;
    const int c = threadIdx.x & 31;
    const int r0 = (threadIdx.x >> 5) * 4;
#pragma unroll
    for (int i = 0; i < 4; ++i)
      tile[r0 + i][c] = kT[(by * 32 + r0 + i) * 128 + bx * 32 + c];
    __syncthreads();
#pragma unroll
    for (int i = 0; i < 4; ++i)
      kTt[(bx * 32 + r0 + i) * 128 + by * 32 + c] = tile[c][r0 + i];
  } else {
    const int t = threadIdx.x;
#pragma unroll
    for (int s = 0; s < 4; ++s) {
      const int idx = (s * 256 + t) * 4;
      float4 v = *(const float4*)&wrel[idx];
      v.x *= v.x; v.y *= v.y; v.z *= v.z; v.w *= v.w;
      *(float4*)&wrel2[idx] = v;
    }
  }
}

// ---------------------------------------------------------------------------
// K1: Q = entity_emb @ qTrans   (Q in d_out; consumed & overwritten later)
// 128 nodes/block, qT LDS-staged: efficient L2 amortization (R5 lesson:
// fusing this into 8-node blocks cost ~170 us of per-block qT re-reads).
// ---------------------------------------------------------------------------
__global__ __launch_bounds__(512) void k_qproj(const float* __restrict__ ent,
                                               const float* __restrict__ qT,
                                               float* __restrict__ Q) {
  __shared__ float sT[D * D];
  __shared__ float rows[D * 128];
  const int t = threadIdx.x;
  const int n0 = blockIdx.x * 128;
#pragma unroll
  for (int s = 0; s < 8; ++s) {
    const int idx = (s * 512 + t) * 4;
    *(float4*)&sT[idx] = *(const float4*)&qT[idx];
  }
  {
    const int g = t & 3;
    const int n = t >> 2;
    const int node = n0 + n;
    if (node < N_ENT) {
      const float* src = ent + (size_t)node * D;
#pragma unroll
      for (int s = 0; s < 8; ++s) {
        const int i = s * 16 + g * 4;
        float4 v = *(const float4*)&src[i];
        rows[(i + 0) * 128 + n] = v.x;
        rows[(i + 1) * 128 + n] = v.y;
        rows[(i + 2) * 128 + n] = v.z;
        rows[(i + 3) * 128 + n] = v.w;
      }
    } else {
#pragma unroll
      for (int s = 0; s < 8; ++s) {
        const int i = s * 16 + g * 4;
        rows[(i + 0) * 128 + n] = 0.f;
        rows[(i + 1) * 128 + n] = 0.f;
        rows[(i + 2) * 128 + n] = 0.f;
        rows[(i + 3) * 128 + n] = 0.f;
      }
    }
  }
  __syncthreads();
  const int jj = t & 15;
  const int ee = t >> 4;
  float acc[4][8];
#pragma unroll
  for (int a = 0; a < 4; ++a)
#pragma unroll
    for (int b = 0; b < 8; ++b) acc[a][b] = 0.f;
#pragma unroll 4
  for (int i = 0; i < D; ++i) {
    float4 b0 = *(float4*)&sT[i * D + jj * 8];
    float4 b1 = *(float4*)&sT[i * D + jj * 8 + 4];
    float4 a0 = *(float4*)&rows[i * 128 + ee * 4];
    float bv[8] = {b0.x, b0.y, b0.z, b0.w, b1.x, b1.y, b1.z, b1.w};
    float av[4] = {a0.x, a0.y, a0.z, a0.w};
#pragma unroll
    for (int a = 0; a < 4; ++a)
#pragma unroll
      for (int b = 0; b < 8; ++b) acc[a][b] = fmaf(av[a], bv[b], acc[a][b]);
  }
#pragma unroll
  for (int a = 0; a < 4; ++a) {
    const int node = n0 + ee * 4 + a;
    if (node < N_ENT) {
      float4 o0 = {acc[a][0], acc[a][1], acc[a][2], acc[a][3]};
      float4 o1 = {acc[a][4], acc[a][5], acc[a][6], acc[a][7]};
      *(float4*)&Q[(size_t)node * D + jj * 8] = o0;
      *(float4*)&Q[(size_t)node * D + jj * 8 + 4] = o1;
    }
  }
}

// ---------------------------------------------------------------------------
// K2: fused attention + S. 512 threads, 8 nodes/block (ONE node per 64-lane
// WAVE, float2 per lane), 20 KB LDS.
// R5 lessons applied:
//   - occupancy is VGPR-tier-gated (64 VGPR -> 16 waves/CU; <=32 -> 32).
//     Full-wave/float2 P2 halves live state (~30 regs) so the
//     __launch_bounds__(512,8) 32-VGPR clamp is ~spill-free -> 4 blk/CU.
//   - QP un-fused (per-8-node qT re-reads cost ~170 us); Q read from global.
//   - P3+P4 fusion kept (kg never hits HBM; WRITE_SIZE was exactly 12.5 MB).
// Phases: P0 stage Q -> P1 P=K^T q -> P2 edge loop -> P3 kg,kg^2 -> P4 S.
// ---------------------------------------------------------------------------
__global__ __launch_bounds__(512, 8) void k_fused(
    const float* __restrict__ ent, const float* __restrict__ wrel,
    const float* __restrict__ kTt, const float* __restrict__ vT,
    const float* __restrict__ wrel2, const float* __restrict__ qkg,
    float* __restrict__ S, const int* __restrict__ off,
    const int2* __restrict__ teP) {
  __shared__ float sQ[8 * 128];    //  4 KB: Q, later kg^2
  __shared__ float sPA[8 * 512];   // 16 KB: P, then Agg (lane-private alias)
  const int t = threadIdx.x;
  const int base = blockIdx.x * 8;
  const int kk = t >> 6;    // wave id = node slot
  const int lane = t & 63;
  const int n = base + kk;

  // P0: stage Q rows (8 x 128 floats, float2 per thread)
  *(float2*)&sQ[kk * 128 + lane * 2] =
      *(const float2*)&qkg[(size_t)n * D + lane * 2];

  // hoisted: CSR range + first edge gather (latency overlaps P1)
  const int eb = off[n];
  const int deg = off[n + 1] - eb;
  float2 xv = {0, 0}, rv = {0, 0};
  if (deg > 0) {
    const int2 pf = teP[eb];
    xv = *(const float2*)&ent[(size_t)pf.x * D + lane * 2];
    rv = *(const float2*)&wrel[(size_t)pf.y * D + lane * 2];
  }
  __syncthreads();

  // P1: P[k,h,i] = sum_c kTt[h*32+c, i] * Q[k, h*32+c].
  // 512 threads: i = t&127, h = t>>7 (one head per quarter), k = 0..7.
  {
    const int i = t & 127;
    const int h = t >> 7;
    float pp[8];
#pragma unroll
    for (int k = 0; k < 8; ++k) pp[k] = 0.f;
#pragma unroll 2
    for (int c4 = 0; c4 < 8; ++c4) {
      const float kv0 = kTt[(h * 32 + c4 * 4 + 0) * 128 + i];
      const float kv1 = kTt[(h * 32 + c4 * 4 + 1) * 128 + i];
      const float kv2 = kTt[(h * 32 + c4 * 4 + 2) * 128 + i];
      const float kv3 = kTt[(h * 32 + c4 * 4 + 3) * 128 + i];
#pragma unroll
      for (int k = 0; k < 8; ++k) {
        const float4 q = *(const float4*)&sQ[k * 128 + h * 32 + c4 * 4];
        pp[k] = fmaf(kv0, q.x, pp[k]);
        pp[k] = fmaf(kv1, q.y, pp[k]);
        pp[k] = fmaf(kv2, q.z, pp[k]);
        pp[k] = fmaf(kv3, q.w, pp[k]);
      }
    }
#pragma unroll
    for (int k = 0; k < 8; ++k) sPA[k * 512 + h * 128 + i] = pp[k];
  }
  __syncthreads();

  // P2: edge loop; one node per 64-lane wave, float2 per lane.
  // lane lp = lane&3 carries head (lp^m) in accumulator b_m.
  {
    const int lp = lane & 3;
    const float2 Pv0 = *(const float2*)&sPA[kk * 512 + 0 * 128 + lane * 2];
    const float2 Pv1 = *(const float2*)&sPA[kk * 512 + 1 * 128 + lane * 2];
    const float2 Pv2 = *(const float2*)&sPA[kk * 512 + 2 * 128 + lane * 2];
    const float2 Pv3 = *(const float2*)&sPA[kk * 512 + 3 * 128 + lane * 2];
    float2 b0 = {0, 0}, b1 = {0, 0}, b2 = {0, 0}, b3 = {0, 0};
    float s0 = 0.f, s1 = 0.f, s2 = 0.f, s3 = 0.f;
    for (int idx = 0; idx < deg; ++idx) {
      const float2 nh = {xv.x * rv.x, xv.y * rv.y};
      if (idx + 1 < deg) {
        const int2 pf = teP[eb + idx + 1];
        xv = *(const float2*)&ent[(size_t)pf.x * D + lane * 2];
        rv = *(const float2*)&wrel[(size_t)pf.y * D + lane * 2];
      }
      float d0 = nh.x * Pv0.x + nh.y * Pv0.y;
      float d1 = nh.x * Pv1.x + nh.y * Pv1.y;
      float d2 = nh.x * Pv2.x + nh.y * Pv2.y;
      float d3 = nh.x * Pv3.x + nh.y * Pv3.y;
      // packed 4-value butterfly over 64 lanes: lane ends with sum d_{lane&3}
      float x01 = (lane & 1) ? d1 : d0;
      float y01 = (lane & 1) ? d0 : d1;
      x01 += __shfl_xor(y01, 1);
      float x23 = (lane & 1) ? d3 : d2;
      float y23 = (lane & 1) ? d2 : d3;
      x23 += __shfl_xor(y23, 1);
      float xa = (lane & 2) ? x23 : x01;
      float xb = (lane & 2) ? x01 : x23;
      xa += __shfl_xor(xb, 2);
      xa += __shfl_xor(xa, 4);
      xa += __shfl_xor(xa, 8);
      xa += __shfl_xor(xa, 16);
      xa += __shfl_xor(xa, 32);
      const float eL = __expf(fminf(fmaxf(xa, -10.f), 10.f));
      const float e0 = eL;                 // head lp
      const float e1 = __shfl_xor(eL, 1);  // head lp^1
      const float e2 = __shfl_xor(eL, 2);  // head lp^2
      const float e3 = __shfl_xor(eL, 3);  // head lp^3
      b0.x = fmaf(e0, nh.x, b0.x); b0.y = fmaf(e0, nh.y, b0.y);
      b1.x = fmaf(e1, nh.x, b1.x); b1.y = fmaf(e1, nh.y, b1.y);
      b2.x = fmaf(e2, nh.x, b2.x); b2.y = fmaf(e2, nh.y, b2.y);
      b3.x = fmaf(e3, nh.x, b3.x); b3.y = fmaf(e3, nh.y, b3.y);
      s0 += e0; s1 += e1; s2 += e2; s3 += e3;
    }
    // b_m/s_m belong to head (lp^m): divide, store at head offset lp^m.
    const float i0 = 1.f / (s0 + 1e-8f);
    const float i1 = 1.f / (s1 + 1e-8f);
    const float i2 = 1.f / (s2 + 1e-8f);
    const float i3 = 1.f / (s3 + 1e-8f);
    float2 o0 = {b0.x * i0, b0.y * i0};
    float2 o1 = {b1.x * i1, b1.y * i1};
    float2 o2 = {b2.x * i2, b2.y * i2};
    float2 o3 = {b3.x * i3, b3.y * i3};
    const int sb = kk * 512 + lane * 2;
    *(float2*)&sPA[sb + ((lp ^ 0) << 7)] = o0;
    *(float2*)&sPA[sb + ((lp ^ 1) << 7)] = o1;
    *(float2*)&sPA[sb + ((lp ^ 2) << 7)] = o2;
    *(float2*)&sPA[sb + ((lp ^ 3) << 7)] = o3;
  }
  __syncthreads();

  // P3: kg[n,c] = sum_d agg[n,h(c),d]*vT[d,c]; kg^2 -> sQ (Q is dead).
  // 512 threads: c = t&127, p = t>>7 -> nodes {p, p+4}.
  {
    const int c = t & 127;
    const int p = t >> 7;
    const int h = c >> 5;
    const float* aggA = &sPA[(p + 0) * 512 + h * 128];
    const float* aggB = &sPA[(p + 4) * 512 + h * 128];
    float accA = 0.f, accB = 0.f;
#pragma unroll 4
    for (int d4 = 0; d4 < 32; ++d4) {
      const float4 aA = *(const float4*)&aggA[d4 * 4];
      const float4 aB = *(const float4*)&aggB[d4 * 4];
      const float v0 = vT[(d4 * 4 + 0) * 128 + c];
      const float v1 = vT[(d4 * 4 + 1) * 128 + c];
      const float v2 = vT[(d4 * 4 + 2) * 128 + c];
      const float v3 = vT[(d4 * 4 + 3) * 128 + c];
      accA = fmaf(aA.x, v0, accA); accA = fmaf(aA.y, v1, accA);
      accA = fmaf(aA.z, v2, accA); accA = fmaf(aA.w, v3, accA);
      accB = fmaf(aB.x, v0, accB); accB = fmaf(aB.y, v1, accB);
      accB = fmaf(aB.z, v2, accB); accB = fmaf(aB.w, v3, accB);
    }
    sQ[(p + 0) * 128 + c] = accA * accA;
    sQ[(p + 4) * 128 + c] = accB * accB;
  }
  __syncthreads();

  // P4: S[n,r] = sum_c kg2[n,c] * wrel2[r,c]; coalesced store. t<256 active.
  if (t < 256) {
    const int nn = t >> 5;  // 0..7
    const int r = t & 31;
    const float* kg2 = &sQ[nn * 128];
    const float* w2 = &wrel2[r * 128];
    float acc = 0.f;
#pragma unroll 4
    for (int c4 = 0; c4 < 32; ++c4) {
      const float4 a = *(const float4*)&kg2[c4 * 4];
      const float4 b = *(const float4*)&w2[c4 * 4];
      acc = fmaf(a.x, b.x, acc); acc = fmaf(a.y, b.y, acc);
      acc = fmaf(a.z, b.z, acc); acc = fmaf(a.w, b.w, acc);
    }
    S[(size_t)(base + nn) * 32 + r] = acc;
  }
}

// ---------------------------------------------------------------------------
// K4: per-node online softmax over w(e)=S[n,ty]*S[tail,ty] + weighted gather.
// ---------------------------------------------------------------------------
__global__ __launch_bounds__(256) void k_out2(
    const float* __restrict__ ent, const float* __restrict__ S,
    const int* __restrict__ off, const int2* __restrict__ teP,
    float* __restrict__ out) {
  const int t = threadIdx.x;
  const int wid = t >> 6;
  const int lane = t & 63;
  const int n = blockIdx.x * 4 + wid;
  if (n >= N_ENT) return;
  const int eb = off[n];
  const int deg = off[n + 1] - eb;
  float accx = 0.f, accy = 0.f;
  float m = 0.f, ssum = 0.f;
  for (int b = 0; b < deg; b += 64) {
    const int idx = b + lane;
    const bool val = idx < deg;
    const int e = eb + (val ? idx : 0);
    const int2 tp = teP[e];
    const int tl = tp.x;
    const int ty = tp.y;
    float w = val ? S[(size_t)n * 32 + ty] * S[(size_t)tl * 32 + ty] : -1.f;
    float cm = w;
#pragma unroll
    for (int k = 1; k < 64; k <<= 1) cm = fmaxf(cm, __shfl_xor(cm, k));
    const float mnew = fmaxf(m, cm);
    const float scale = __expf(m - mnew);
    const float el = val ? __expf(w - mnew) : 0.f;
    float cs = el;
#pragma unroll
    for (int k = 1; k < 64; k <<= 1) cs += __shfl_xor(cs, k);
    ssum = ssum * scale + cs;
    accx *= scale;
    accy *= scale;
    const int cnt = (deg - b < 64) ? deg - b : 64;
    {
      const int tl0 = __shfl(tl, 0);
      float2 xr = *(const float2*)&ent[(size_t)tl0 * D + lane * 2];
      for (int j = 0; j < cnt; ++j) {
        const float sj = __shfl(el, j);
        const float2 cx = xr;
        if (j + 1 < cnt) {
          const int tlj = __shfl(tl, j + 1);
          xr = *(const float2*)&ent[(size_t)tlj * D + lane * 2];
        }
        accx = fmaf(sj, cx.x, accx);
        accy = fmaf(sj, cx.y, accy);
      }
    }
    m = mnew;
  }
  const float inv = (deg > 0) ? 1.f / ssum : 0.f;
  float2 o = {accx * inv, accy * inv};
  *(float2*)&out[(size_t)n * D + lane * 2] = o;
}

// ---------------------------------------------------------------------------
// Workspace (byte-identical footprint to the proven round-2 layout):
//   S [N*32] fp32; off[N+2], cur[N], deg[N], bsum/bbase[SCAN_NB] int;
//   teP [E] int2; kTt [128*128] fp32. wrel2 ALIASES cur (dead after scatter).
// d_out timeline: Q (k_qproj) -> consumed by k_fused -> output (k_out2).
// ---------------------------------------------------------------------------
extern "C" void kernel_launch(void* const* d_in, const int* in_sizes, int n_in,
                              void* d_out, int out_size, void* d_ws,
                              size_t ws_size, hipStream_t stream) {
  const float* ent = (const float*)d_in[0];
  const float* wrel = (const float*)d_in[3];
  const float* qT = (const float*)d_in[4];
  const float* kT = (const float*)d_in[5];
  const float* vT = (const float*)d_in[6];
  const int* eidx = (const int*)d_in[7];
  const int* etype = (const int*)d_in[8];
  const int* head = eidx;
  const int* tail = eidx + N_EDGE;

  float* S = (float*)d_ws;
  int* off = (int*)(S + (size_t)N_ENT * 32);
  int* cur = off + (N_ENT + 2);  // +2 keeps teP 8-byte aligned
  int* deg = cur + N_ENT;
  int* bsum = deg + N_ENT;
  int* bbase = bsum + SCAN_NB;
  int2* teP = (int2*)(bbase + SCAN_NB);
  float* kTt = (float*)(teP + N_EDGE);
  float* wrel2 = (float*)cur;  // 16 KB of the 400 KB dead cursor array
  float* qkg = (float*)d_out;

  hipMemsetAsync(deg, 0, N_ENT * sizeof(int), stream);
  k_hist<<<(N_EDGE + 255) / 256, 256, 0, stream>>>(head, deg);
  k_scan1<<<SCAN_NB, 256, 0, stream>>>(deg, bsum);
  k_scan2<<<1, 256, 0, stream>>>(bsum, bbase, off);
  k_scan3<<<SCAN_NB, 256, 0, stream>>>(deg, bbase, off, cur);
  k_scatter<<<(N_EDGE + 255) / 256, 256, 0, stream>>>(head, tail, etype, cur,
                                                      teP);
  k_prep<<<17, 256, 0, stream>>>(kT, kTt, wrel, wrel2);
  k_qproj<<<(N_ENT + 127) / 128, 512, 0, stream>>>(ent, qT, qkg);
  k_fused<<<N_ENT / 8, 512, 0, stream>>>(ent, wrel, kTt, vT, wrel2, qkg, S,
                                         off, teP);
  k_out2<<<(N_ENT + 3) / 4, 256, 0, stream>>>(ent, S, off, teP, qkg);
}